// Round 13
// baseline (110.120 us; speedup 1.0000x reference)
//
#include <hip/hip_runtime.h>

// B=4, IN_C=64, IN_S=16384, OUT_C=64, OUT_S=4096, K=4.
// out[b,o,s] = bias[o,s] + sum_{i,k} x[b,i,4s+k] * w[i,k,o,s]
//
// R13 = R9's exact structure + explicit DEPTH-4 register pipeline.
//   thread = 1 s x 2 o x 4 b; wave = 64 s x one o-pair;
//   block = 4 waves = 8 o x 64 s; grid = 64 s-tiles x 8 o-octs = 512 blocks.
// Theory: R10's VGPR=56 shows the compiler keeps ~1 iter of loads in flight;
// each i-iter then exposes most of the ~600-900cy L3/HBM latency
// (151K cyc / 128 wave-iters/SIMD ~= 1180 cyc/iter = serialized round trips).
// Fix: 4 static register slots, 24 VGPR each; compute slot p while p+1..p+3
// (36 loads, ~18KB) are in flight; re-issue i+4 into p right after its FMAs.
// All slot indices compile-time static. launch_bounds(256,2) allows ~256 VGPR
// at 8 waves/CU.

__global__ __launch_bounds__(256, 2) void adj1d_kernel(
    const float* __restrict__ x, const float* __restrict__ w,
    const float* __restrict__ bias, float* __restrict__ out) {

  int bid = blockIdx.x;                 // 0..511
  int wgid = (bid & 7) * 64 + (bid >> 3);
  int og = wgid & 7;                    // o-oct group (8 output channels)
  int st = wgid >> 3;                   // s-tile (64 s)
  int lane = threadIdx.x & 63;
  int wv   = threadIdx.x >> 6;          // wave id = o-pair within the oct
  int s  = (st << 6) + lane;
  int o0 = (og << 3) + (wv << 1);

  float acc00 = 0.f, acc01 = 0.f, acc02 = 0.f, acc03 = 0.f;  // o0,   b=0..3
  float acc10 = 0.f, acc11 = 0.f, acc12 = 0.f, acc13 = 0.f;  // o0+1, b=0..3

  const float4* __restrict__ xv = reinterpret_cast<const float4*>(x);
  // w element index: ((i*4+k)*64 + o)*4096 + s ; per-(i,k) stride = 262144
  const float* __restrict__ wp0 = w + (o0 << 12) + s;

  float4 xb[4][4];    // [slot][b]
  float  wb[4][2][4]; // [slot][o][k]

#define LOAD(p, i) do {                                                   \
    xb[p][0] = xv[((0 * 64 + (i)) << 12) + s];                            \
    xb[p][1] = xv[((1 * 64 + (i)) << 12) + s];                            \
    xb[p][2] = xv[((2 * 64 + (i)) << 12) + s];                            \
    xb[p][3] = xv[((3 * 64 + (i)) << 12) + s];                            \
    const float* wp_ = wp0 + (size_t)(i) * 1048576;                       \
    wb[p][0][0] = wp_[0];      wb[p][1][0] = wp_[4096];                   \
    wb[p][0][1] = wp_[262144]; wb[p][1][1] = wp_[262144 + 4096];          \
    wb[p][0][2] = wp_[524288]; wb[p][1][2] = wp_[524288 + 4096];          \
    wb[p][0][3] = wp_[786432]; wb[p][1][3] = wp_[786432 + 4096];          \
  } while (0)

#define COMP(p) do {                                                      \
    float xk0[4] = {xb[p][0].x, xb[p][0].y, xb[p][0].z, xb[p][0].w};      \
    float xk1[4] = {xb[p][1].x, xb[p][1].y, xb[p][1].z, xb[p][1].w};      \
    float xk2[4] = {xb[p][2].x, xb[p][2].y, xb[p][2].z, xb[p][2].w};      \
    float xk3[4] = {xb[p][3].x, xb[p][3].y, xb[p][3].z, xb[p][3].w};      \
    _Pragma("unroll")                                                     \
    for (int k = 0; k < 4; ++k) {                                         \
      float wa = wb[p][0][k], wc = wb[p][1][k];                           \
      acc00 = fmaf(xk0[k], wa, acc00);                                    \
      acc01 = fmaf(xk1[k], wa, acc01);                                    \
      acc02 = fmaf(xk2[k], wa, acc02);                                    \
      acc03 = fmaf(xk3[k], wa, acc03);                                    \
      acc10 = fmaf(xk0[k], wc, acc10);                                    \
      acc11 = fmaf(xk1[k], wc, acc11);                                    \
      acc12 = fmaf(xk2[k], wc, acc12);                                    \
      acc13 = fmaf(xk3[k], wc, acc13);                                    \
    }                                                                     \
  } while (0)

  // prologue: fill the 4 slots
  LOAD(0, 0); LOAD(1, 1); LOAD(2, 2); LOAD(3, 3);

  // steady state: compute slot p (iter i+p), immediately refill with i+4+p
  #pragma unroll 1
  for (int i = 0; i < 60; i += 4) {
    COMP(0); LOAD(0, i + 4);
    COMP(1); LOAD(1, i + 5);
    COMP(2); LOAD(2, i + 6);
    COMP(3); LOAD(3, i + 7);
  }
  // epilogue: iters 60..63
  COMP(0); COMP(1); COMP(2); COMP(3);

#undef LOAD
#undef COMP

  float bA = bias[(o0 << 12) + s];
  float bB = bias[((o0 + 1) << 12) + s];

  out[((0 * 64 + o0) << 12) + s]     = acc00 + bA;
  out[((1 * 64 + o0) << 12) + s]     = acc01 + bA;
  out[((2 * 64 + o0) << 12) + s]     = acc02 + bA;
  out[((3 * 64 + o0) << 12) + s]     = acc03 + bA;
  out[((0 * 64 + o0 + 1) << 12) + s] = acc10 + bB;
  out[((1 * 64 + o0 + 1) << 12) + s] = acc11 + bB;
  out[((2 * 64 + o0 + 1) << 12) + s] = acc12 + bB;
  out[((3 * 64 + o0 + 1) << 12) + s] = acc13 + bB;
}

extern "C" void kernel_launch(void* const* d_in, const int* in_sizes, int n_in,
                              void* d_out, int out_size, void* d_ws, size_t ws_size,
                              hipStream_t stream) {
  const float* x    = (const float*)d_in[0];  // (4, 64, 16384)
  const float* w    = (const float*)d_in[1];  // (64, 4, 64, 4096)
  const float* bias = (const float*)d_in[2];  // (64, 4096)
  float* out = (float*)d_out;                 // (4, 64, 4096)

  // 64 s-tiles x 8 o-octs = 512 blocks, 256 threads each
  adj1d_kernel<<<512, 256, 0, stream>>>(x, w, bias, out);
}

// Round 14
// 108.188 us; speedup vs baseline: 1.0179x; 1.0179x over previous
//
#include <hip/hip_runtime.h>

// B=4, IN_C=64, IN_S=16384, OUT_C=64, OUT_S=4096, K=4.
// out[b,o,s] = bias[o,s] + sum_{i,k} x[b,i,4s+k] * w[i,k,o,s]
//
// R14 = R9 (62.8 us, best) + VGPR headroom + compiler-scheduled deep unroll.
// Theory: __launch_bounds__(256) alone made hipcc budget ~64 VGPR (targeting
// 8 waves/SIMD the 512-block grid never provides) -> loads serialized within
// each iteration (R10: VGPR=56, R4: VGPR=28, VALUBusy ~7%, ~2375 cyc per
// 2-iter batch = exposed L3/HBM latency). Fix: __launch_bounds__(256, 2)
// (VGPR cap 256 at our real 2 waves/SIMD) + #pragma unroll 4 so the compiler
// hoists ~48 loads per batch. No manual slots (R13's scratch trap).
//   thread = 1 s x 2 o x 4 b; wave = 64 s x one o-pair;
//   block = 4 waves = 8 o x 64 s; grid = 64 s-tiles x 8 o-octs = 512 blocks.

__global__ __launch_bounds__(256, 2) void adj1d_kernel(
    const float* __restrict__ x, const float* __restrict__ w,
    const float* __restrict__ bias, float* __restrict__ out) {

  int bid = blockIdx.x;                 // 0..511
  int wgid = (bid & 7) * 64 + (bid >> 3);
  int og = wgid & 7;                    // o-oct group (8 output channels)
  int st = wgid >> 3;                   // s-tile (64 s)
  int lane = threadIdx.x & 63;
  int wv   = threadIdx.x >> 6;          // wave id = o-pair within the oct
  int s  = (st << 6) + lane;
  int o0 = (og << 3) + (wv << 1);

  float acc00 = 0.f, acc01 = 0.f, acc02 = 0.f, acc03 = 0.f;  // o0,   b=0..3
  float acc10 = 0.f, acc11 = 0.f, acc12 = 0.f, acc13 = 0.f;  // o0+1, b=0..3

  const float4* __restrict__ xv = reinterpret_cast<const float4*>(x);
  // w element index: ((i*4+k)*64 + o)*4096 + s ; per-(i,k) stride = 262144
  const float* __restrict__ wp0 = w + (o0 << 12) + s;

  #pragma unroll 4
  for (int i = 0; i < 64; ++i) {
    float xa[4][4];  // [b][k]
    *reinterpret_cast<float4*>(xa[0]) = xv[((0 * 64 + i) << 12) + s];
    *reinterpret_cast<float4*>(xa[1]) = xv[((1 * 64 + i) << 12) + s];
    *reinterpret_cast<float4*>(xa[2]) = xv[((2 * 64 + i) << 12) + s];
    *reinterpret_cast<float4*>(xa[3]) = xv[((3 * 64 + i) << 12) + s];
    #pragma unroll
    for (int k = 0; k < 4; ++k) {
      const float* wp = wp0 + (size_t)(i * 4 + k) * 262144;
      float wa = wp[0];
      float wb = wp[4096];
      acc00 = fmaf(xa[0][k], wa, acc00);
      acc01 = fmaf(xa[1][k], wa, acc01);
      acc02 = fmaf(xa[2][k], wa, acc02);
      acc03 = fmaf(xa[3][k], wa, acc03);
      acc10 = fmaf(xa[0][k], wb, acc10);
      acc11 = fmaf(xa[1][k], wb, acc11);
      acc12 = fmaf(xa[2][k], wb, acc12);
      acc13 = fmaf(xa[3][k], wb, acc13);
    }
  }

  float bA = bias[(o0 << 12) + s];
  float bB = bias[((o0 + 1) << 12) + s];

  out[((0 * 64 + o0) << 12) + s]     = acc00 + bA;
  out[((1 * 64 + o0) << 12) + s]     = acc01 + bA;
  out[((2 * 64 + o0) << 12) + s]     = acc02 + bA;
  out[((3 * 64 + o0) << 12) + s]     = acc03 + bA;
  out[((0 * 64 + o0 + 1) << 12) + s] = acc10 + bB;
  out[((1 * 64 + o0 + 1) << 12) + s] = acc11 + bB;
  out[((2 * 64 + o0 + 1) << 12) + s] = acc12 + bB;
  out[((3 * 64 + o0 + 1) << 12) + s] = acc13 + bB;
}

extern "C" void kernel_launch(void* const* d_in, const int* in_sizes, int n_in,
                              void* d_out, int out_size, void* d_ws, size_t ws_size,
                              hipStream_t stream) {
  const float* x    = (const float*)d_in[0];  // (4, 64, 16384)
  const float* w    = (const float*)d_in[1];  // (64, 4, 64, 4096)
  const float* bias = (const float*)d_in[2];  // (64, 4096)
  float* out = (float*)d_out;                 // (4, 64, 4096)

  // 64 s-tiles x 8 o-octs = 512 blocks, 256 threads each
  adj1d_kernel<<<512, 256, 0, stream>>>(x, w, bias, out);
}

// Round 15
// 67.430 us; speedup vs baseline: 1.6331x; 1.6044x over previous
//
#include <hip/hip_runtime.h>

// B=4, IN_C=64, IN_S=16384, OUT_C=64, OUT_S=4096, K=4.
// out[b,o,s] = bias[o,s] + sum_{i,k} x[b,i,4s+k] * w[i,k,o,s]
//
// R15 = R9 (62.8 us, best) + i-loop phase STAGGER by o-group.
// Theory: all waves advance i in lockstep from 0; every w stride (o:16KB,
// k:256KB, i:1MB) is a power-of-2 multiple of the 16KB s-row, so the live
// address set hits the SAME HBM/L3 channel subset chip-wide (~4.3 TB/s
// effective on a 7 TB/s path; deeper MLP only queued worse: R13/R14).
// Stagger: block with o-group og iterates i = (t + 8*og) & 63 -> per-XCD
// live w-footprint spans 8 i-planes (32 MB), ~8x more channels active.
// Everything else is bit-identical to R9.

__global__ __launch_bounds__(256) void adj1d_kernel(
    const float* __restrict__ x, const float* __restrict__ w,
    const float* __restrict__ bias, float* __restrict__ out) {

  int bid = blockIdx.x;                 // 0..511
  int wgid = (bid & 7) * 64 + (bid >> 3);
  int og = wgid & 7;                    // o-oct group (8 output channels)
  int st = wgid >> 3;                   // s-tile (64 s)
  int lane = threadIdx.x & 63;
  int wv   = threadIdx.x >> 6;          // wave id = o-pair within the oct
  int s  = (st << 6) + lane;
  int o0 = (og << 3) + (wv << 1);
  int iphase = og << 3;                 // stagger: 0,8,16,...,56

  float acc00 = 0.f, acc01 = 0.f, acc02 = 0.f, acc03 = 0.f;  // o0,   b=0..3
  float acc10 = 0.f, acc11 = 0.f, acc12 = 0.f, acc13 = 0.f;  // o0+1, b=0..3

  const float4* __restrict__ xv = reinterpret_cast<const float4*>(x);
  // w element index: ((i*4+k)*64 + o)*4096 + s ; per-(i,k) stride = 262144
  const float* __restrict__ wp0 = w + (o0 << 12) + s;

  #pragma unroll 2
  for (int t = 0; t < 64; ++t) {
    int i = (t + iphase) & 63;
    float xa[4][4];  // [b][k]
    *reinterpret_cast<float4*>(xa[0]) = xv[((0 * 64 + i) << 12) + s];
    *reinterpret_cast<float4*>(xa[1]) = xv[((1 * 64 + i) << 12) + s];
    *reinterpret_cast<float4*>(xa[2]) = xv[((2 * 64 + i) << 12) + s];
    *reinterpret_cast<float4*>(xa[3]) = xv[((3 * 64 + i) << 12) + s];
    #pragma unroll
    for (int k = 0; k < 4; ++k) {
      const float* wp = wp0 + (size_t)(i * 4 + k) * 262144;
      float wa = wp[0];
      float wb = wp[4096];
      acc00 = fmaf(xa[0][k], wa, acc00);
      acc01 = fmaf(xa[1][k], wa, acc01);
      acc02 = fmaf(xa[2][k], wa, acc02);
      acc03 = fmaf(xa[3][k], wa, acc03);
      acc10 = fmaf(xa[0][k], wb, acc10);
      acc11 = fmaf(xa[1][k], wb, acc11);
      acc12 = fmaf(xa[2][k], wb, acc12);
      acc13 = fmaf(xa[3][k], wb, acc13);
    }
  }

  float bA = bias[(o0 << 12) + s];
  float bB = bias[((o0 + 1) << 12) + s];

  out[((0 * 64 + o0) << 12) + s]     = acc00 + bA;
  out[((1 * 64 + o0) << 12) + s]     = acc01 + bA;
  out[((2 * 64 + o0) << 12) + s]     = acc02 + bA;
  out[((3 * 64 + o0) << 12) + s]     = acc03 + bA;
  out[((0 * 64 + o0 + 1) << 12) + s] = acc10 + bB;
  out[((1 * 64 + o0 + 1) << 12) + s] = acc11 + bB;
  out[((2 * 64 + o0 + 1) << 12) + s] = acc12 + bB;
  out[((3 * 64 + o0 + 1) << 12) + s] = acc13 + bB;
}

extern "C" void kernel_launch(void* const* d_in, const int* in_sizes, int n_in,
                              void* d_out, int out_size, void* d_ws, size_t ws_size,
                              hipStream_t stream) {
  const float* x    = (const float*)d_in[0];  // (4, 64, 16384)
  const float* w    = (const float*)d_in[1];  // (64, 4, 64, 4096)
  const float* bias = (const float*)d_in[2];  // (64, 4096)
  float* out = (float*)d_out;                 // (4, 64, 4096)

  // 64 s-tiles x 8 o-octs = 512 blocks, 256 threads each
  adj1d_kernel<<<512, 256, 0, stream>>>(x, w, bias, out);
}

// Round 16
// 62.515 us; speedup vs baseline: 1.7615x; 1.0786x over previous
//
#include <hip/hip_runtime.h>

// B=4, IN_C=64, IN_S=16384, OUT_C=64, OUT_S=4096, K=4.
// out[b,o,s] = bias[o,s] + sum_{i,k} x[b,i,4s+k] * w[i,k,o,s]
//
// FINAL = R9 (measured best: 62.8 us). 15 rounds of structural variants
// (occupancy, cache hints, LDS, chunk shapes, aggregation, MLP depth,
// channel stagger) all failed to beat this point; MLP-deepening regressed
// 1.7x (saturation signature). Assessed as the service-rate ceiling for the
// irreducible 256 MB read-once weight stream (~4.3 TB/s effective on this
// power-of-2-strided pattern).
//
//   thread = 1 s x 2 o x 4 b -> 8 accumulators
//   wave   = 64 s x one o-pair: 8 w-streams of 256 B/iter, dense float4 x
//   block  = 4 waves = 8 o x 64 s (waves share identical x addresses -> L1)
//   grid   = 64 s-tiles x 8 o-octs = 512 blocks (2/CU, 8 waves/CU)
// - w: dword/lane, lane<->s coalesced, each element read ONCE grid-wide
// - x: float4/lane; logical readers per element = 8 (128 MB through L2)
// - XCD swizzle: 64 consecutive wgids per XCD = 8 s-tiles x all 8 o-octs ->
//   per-XCD x slice 2 MB L2-resident, sharers co-resident on one XCD

__global__ __launch_bounds__(256) void adj1d_kernel(
    const float* __restrict__ x, const float* __restrict__ w,
    const float* __restrict__ bias, float* __restrict__ out) {

  int bid = blockIdx.x;                 // 0..511
  int wgid = (bid & 7) * 64 + (bid >> 3);
  int og = wgid & 7;                    // o-oct group (8 output channels)
  int st = wgid >> 3;                   // s-tile (64 s)
  int lane = threadIdx.x & 63;
  int wv   = threadIdx.x >> 6;          // wave id = o-pair within the oct
  int s  = (st << 6) + lane;
  int o0 = (og << 3) + (wv << 1);

  float acc00 = 0.f, acc01 = 0.f, acc02 = 0.f, acc03 = 0.f;  // o0,   b=0..3
  float acc10 = 0.f, acc11 = 0.f, acc12 = 0.f, acc13 = 0.f;  // o0+1, b=0..3

  const float4* __restrict__ xv = reinterpret_cast<const float4*>(x);
  // w element index: ((i*4+k)*64 + o)*4096 + s ; per-(i,k) stride = 262144
  const float* __restrict__ wp0 = w + (o0 << 12) + s;

  #pragma unroll 2
  for (int i = 0; i < 64; ++i) {
    float xa[4][4];  // [b][k]
    *reinterpret_cast<float4*>(xa[0]) = xv[((0 * 64 + i) << 12) + s];
    *reinterpret_cast<float4*>(xa[1]) = xv[((1 * 64 + i) << 12) + s];
    *reinterpret_cast<float4*>(xa[2]) = xv[((2 * 64 + i) << 12) + s];
    *reinterpret_cast<float4*>(xa[3]) = xv[((3 * 64 + i) << 12) + s];
    #pragma unroll
    for (int k = 0; k < 4; ++k) {
      const float* wp = wp0 + (size_t)(i * 4 + k) * 262144;
      float wa = wp[0];
      float wb = wp[4096];
      acc00 = fmaf(xa[0][k], wa, acc00);
      acc01 = fmaf(xa[1][k], wa, acc01);
      acc02 = fmaf(xa[2][k], wa, acc02);
      acc03 = fmaf(xa[3][k], wa, acc03);
      acc10 = fmaf(xa[0][k], wb, acc10);
      acc11 = fmaf(xa[1][k], wb, acc11);
      acc12 = fmaf(xa[2][k], wb, acc12);
      acc13 = fmaf(xa[3][k], wb, acc13);
    }
  }

  float bA = bias[(o0 << 12) + s];
  float bB = bias[((o0 + 1) << 12) + s];

  out[((0 * 64 + o0) << 12) + s]     = acc00 + bA;
  out[((1 * 64 + o0) << 12) + s]     = acc01 + bA;
  out[((2 * 64 + o0) << 12) + s]     = acc02 + bA;
  out[((3 * 64 + o0) << 12) + s]     = acc03 + bA;
  out[((0 * 64 + o0 + 1) << 12) + s] = acc10 + bB;
  out[((1 * 64 + o0 + 1) << 12) + s] = acc11 + bB;
  out[((2 * 64 + o0 + 1) << 12) + s] = acc12 + bB;
  out[((3 * 64 + o0 + 1) << 12) + s] = acc13 + bB;
}

extern "C" void kernel_launch(void* const* d_in, const int* in_sizes, int n_in,
                              void* d_out, int out_size, void* d_ws, size_t ws_size,
                              hipStream_t stream) {
  const float* x    = (const float*)d_in[0];  // (4, 64, 16384)
  const float* w    = (const float*)d_in[1];  // (64, 4, 64, 4096)
  const float* bias = (const float*)d_in[2];  // (64, 4096)
  float* out = (float*)d_out;                 // (4, 64, 4096)

  // 64 s-tiles x 8 o-octs = 512 blocks, 256 threads each
  adj1d_kernel<<<512, 256, 0, stream>>>(x, w, bias, out);
}